// Round 6
// baseline (770.310 us; speedup 1.0000x reference)
//
#include <hip/hip_runtime.h>
#include <math.h>

#define T_STEPS 30
#define BATCH   64
#define HID     1024
#define VOCABN  32000
#define G3      3072
#define ROWS    (T_STEPS * BATCH)   // 1920
#define OUT_HID_OFF ((size_t)BATCH * T_STEPS * VOCABN)  // 61,440,000
#define NBY 15
#define NBX 250
#define NPART 500

typedef __attribute__((ext_vector_type(8))) short bf16x8;
typedef __attribute__((ext_vector_type(4))) float f32x4;

__device__ __forceinline__ unsigned short f2bf(float f) {
    union { float f; unsigned u; } x; x.f = f;
    unsigned r = x.u + 0x7fffu + ((x.u >> 16) & 1u);
    return (unsigned short)(r >> 16);
}

__device__ __forceinline__ void gld_lds16(const unsigned short* g, unsigned short* l) {
    __builtin_amdgcn_global_load_lds(
        (const __attribute__((address_space(1))) unsigned*)g,
        (__attribute__((address_space(3))) unsigned*)l, 16, 0, 0);
}

// ---------------------------------------------------------------- fp32 -> bf16 (RNE)
__global__ __launch_bounds__(256) void f32_to_bf16(const float* __restrict__ src,
                                                   unsigned short* __restrict__ dst, int n4) {
    int i = blockIdx.x * 256 + threadIdx.x;
    int stride = gridDim.x * 256;
    for (; i < n4; i += stride) {
        float4 v = ((const float4*)src)[i];
        ushort4 o;
        o.x = f2bf(v.x); o.y = f2bf(v.y); o.z = f2bf(v.z); o.w = f2bf(v.w);
        ((ushort4*)dst)[i] = o;
    }
}

// ---------------------------------------------------------------- X = relu(emb[tok]) -> bf16
__global__ __launch_bounds__(256) void embed_relu_bf16(const int* __restrict__ target,
                                                       const float* __restrict__ emb,
                                                       unsigned short* __restrict__ X) {
    int bid = blockIdx.x;           // t*64 + b
    int t = bid >> 6, b = bid & 63;
    int tok = (t == 0) ? 0 : target[b * T_STEPS + (t - 1)];
    const float4* src = (const float4*)(emb + (size_t)tok * HID);
    float4 v = src[threadIdx.x];
    ushort4 o;
    o.x = f2bf(fmaxf(v.x, 0.f)); o.y = f2bf(fmaxf(v.y, 0.f));
    o.z = f2bf(fmaxf(v.z, 0.f)); o.w = f2bf(fmaxf(v.w, 0.f));
    ((ushort4*)(X + (size_t)bid * HID))[threadIdx.x] = o;
}

// ---------------------------------------------------------------- barrier flags init (64 flags)
__global__ void init_bar(unsigned int* bar) {
    if (threadIdx.x < 64) bar[threadIdx.x] = 0u;
}

// ---------------------------------------------------------------- gi GEMM
__global__ __launch_bounds__(256) void gemm_mfma_bt(const unsigned short* __restrict__ A,
                                                    const unsigned short* __restrict__ W,
                                                    const float* __restrict__ bias,
                                                    float* __restrict__ out,
                                                    int N, int K) {
    __shared__ unsigned short As[128 * 64];
    __shared__ unsigned short Bs[128 * 64];
    int tid  = threadIdx.x;
    int lane = tid & 63;
    int wid  = tid >> 6;
    int wm   = wid >> 1, wn = wid & 1;
    const int bM = blockIdx.y * 128;
    const int bN = blockIdx.x * 128;

    f32x4 acc[4][4];
#pragma unroll
    for (int i = 0; i < 4; ++i)
#pragma unroll
        for (int j = 0; j < 4; ++j) acc[i][j] = (f32x4){0.f, 0.f, 0.f, 0.f};

    int sr[4], sc[4];
#pragma unroll
    for (int q = 0; q < 4; ++q) {
        sr[q] = (wid * 4 + q) * 8 + (lane >> 3);
        sc[q] = (lane & 7) ^ (sr[q] & 7);
    }

    for (int kt = 0; kt < K; kt += 64) {
        __syncthreads();
#pragma unroll
        for (int q = 0; q < 4; ++q) {
            gld_lds16(A + (size_t)(bM + sr[q]) * K + kt + sc[q] * 8, As + (wid * 4 + q) * 512);
            gld_lds16(W + (size_t)(bN + sr[q]) * K + kt + sc[q] * 8, Bs + (wid * 4 + q) * 512);
        }
        __syncthreads();

#pragma unroll
        for (int ks = 0; ks < 2; ++ks) {
            bf16x8 a[4], b[4];
#pragma unroll
            for (int mf = 0; mf < 4; ++mf) {
                int r  = wm * 64 + mf * 16 + (lane & 15);
                int ch = (ks * 4 + (lane >> 4)) ^ (r & 7);
                a[mf] = *(const bf16x8*)(As + r * 64 + ch * 8);
            }
#pragma unroll
            for (int nf = 0; nf < 4; ++nf) {
                int r  = wn * 64 + nf * 16 + (lane & 15);
                int ch = (ks * 4 + (lane >> 4)) ^ (r & 7);
                b[nf] = *(const bf16x8*)(Bs + r * 64 + ch * 8);
            }
#pragma unroll
            for (int mf = 0; mf < 4; ++mf)
#pragma unroll
                for (int nf = 0; nf < 4; ++nf)
                    acc[mf][nf] = __builtin_amdgcn_mfma_f32_16x16x32_bf16(
                        a[mf], b[nf], acc[mf][nf], 0, 0, 0);
        }
    }

    int rif = (lane >> 4) * 4;
    int col = lane & 15;
#pragma unroll
    for (int mf = 0; mf < 4; ++mf) {
#pragma unroll
        for (int j = 0; j < 4; ++j) {
            int gr = bM + wm * 64 + mf * 16 + rif + j;
#pragma unroll
            for (int nf = 0; nf < 4; ++nf) {
                int gc = bN + wn * 64 + nf * 16 + col;
                out[(size_t)gr * N + gc] = acc[mf][nf][j] + bias[gc];
            }
        }
    }
}

// ---------------------------------------------------------------- logits GEMM + permute + softmax partials
__global__ __launch_bounds__(256) void gemm_logits(const unsigned short* __restrict__ A,
                                                   const unsigned short* __restrict__ W,
                                                   const float* __restrict__ bias,
                                                   float* __restrict__ out,
                                                   float2* __restrict__ pstat) {
    __shared__ unsigned short As[128 * 64];
    __shared__ unsigned short Bs[128 * 64];
    int bx = blockIdx.x;
    int by = blockIdx.y;
    const int bM = by * 128;
    const int bN = bx * 128;
    const int K = HID;

    int tid  = threadIdx.x;
    int lane = tid & 63;
    int wid  = tid >> 6;
    int wm   = wid >> 1, wn = wid & 1;

    f32x4 acc[4][4];
#pragma unroll
    for (int i = 0; i < 4; ++i)
#pragma unroll
        for (int j = 0; j < 4; ++j) acc[i][j] = (f32x4){0.f, 0.f, 0.f, 0.f};

    int sr[4], sc[4];
#pragma unroll
    for (int q = 0; q < 4; ++q) {
        sr[q] = (wid * 4 + q) * 8 + (lane >> 3);
        sc[q] = (lane & 7) ^ (sr[q] & 7);
    }

    for (int kt = 0; kt < K; kt += 64) {
        __syncthreads();
#pragma unroll
        for (int q = 0; q < 4; ++q) {
            gld_lds16(A + (size_t)(bM + sr[q]) * K + kt + sc[q] * 8, As + (wid * 4 + q) * 512);
            gld_lds16(W + (size_t)(bN + sr[q]) * K + kt + sc[q] * 8, Bs + (wid * 4 + q) * 512);
        }
        __syncthreads();

#pragma unroll
        for (int ks = 0; ks < 2; ++ks) {
            bf16x8 a[4], b[4];
#pragma unroll
            for (int mf = 0; mf < 4; ++mf) {
                int r  = wm * 64 + mf * 16 + (lane & 15);
                int ch = (ks * 4 + (lane >> 4)) ^ (r & 7);
                a[mf] = *(const bf16x8*)(As + r * 64 + ch * 8);
            }
#pragma unroll
            for (int nf = 0; nf < 4; ++nf) {
                int r  = wn * 64 + nf * 16 + (lane & 15);
                int ch = (ks * 4 + (lane >> 4)) ^ (r & 7);
                b[nf] = *(const bf16x8*)(Bs + r * 64 + ch * 8);
            }
#pragma unroll
            for (int mf = 0; mf < 4; ++mf)
#pragma unroll
                for (int nf = 0; nf < 4; ++nf)
                    acc[mf][nf] = __builtin_amdgcn_mfma_f32_16x16x32_bf16(
                        a[mf], b[nf], acc[mf][nf], 0, 0, 0);
        }
    }

    int rif = (lane >> 4) * 4;
    int col = lane & 15;
#pragma unroll
    for (int mf = 0; mf < 4; ++mf) {
#pragma unroll
        for (int j = 0; j < 4; ++j) {
            int gr = bM + wm * 64 + mf * 16 + rif + j;
            int t = gr >> 6, b = gr & 63;
            int prow = b * T_STEPS + t;
            float v[4];
            float mx = -1e30f;
#pragma unroll
            for (int nf = 0; nf < 4; ++nf) {
                int gc = bN + wn * 64 + nf * 16 + col;
                v[nf] = acc[mf][nf][j] + bias[gc];
                out[(size_t)prow * VOCABN + gc] = v[nf];
                mx = fmaxf(mx, v[nf]);
            }
#pragma unroll
            for (int off = 1; off < 16; off <<= 1) mx = fmaxf(mx, __shfl_xor(mx, off, 64));
            float se = 0.f;
#pragma unroll
            for (int nf = 0; nf < 4; ++nf) se += __expf(v[nf] - mx);
#pragma unroll
            for (int off = 1; off < 16; off <<= 1) se += __shfl_xor(se, off, 64);
            if (col == 0) pstat[(size_t)prow * NPART + bx * 2 + wn] = make_float2(mx, se);
        }
    }
}

// ---------------------------------------------------------------- persistent 30-step GRU
// 64 blocks x 256 threads (cooperative). Block owns m in [bid*16, bid*16+16).
// W panel LDS-resident; h exchange via agent-scope (sc1) loads/stores.
// Barrier = flag vector: one release store per block + 64-lane parallel poll
// (replaces round-5's serialized fetch_add chain on a single counter).
__global__ __launch_bounds__(256) void gru_persistent(
    const unsigned short* __restrict__ h0b,   // [64][1024] bf16
    const float* __restrict__ enc_h,          // [64][1024] fp32
    const unsigned short* __restrict__ Whh,   // [3072][1024] bf16
    const float* __restrict__ b_hh,
    const float* __restrict__ gi,             // [30][64][3072] fp32
    unsigned short* __restrict__ Hall,        // [30][64][1024] bf16
    float* __restrict__ h_final,              // [64][1024] fp32
    unsigned int* __restrict__ flags)         // [64] zeroed per launch
{
    __shared__ unsigned short Wlds[48 * 1024];   // 96 KB: slot[(kt*3+g)*64 + lane] = 8 bf16
    int tid  = threadIdx.x;
    int lane = tid & 63;
    int wq   = tid >> 6;            // batch quarter
    int l15  = lane & 15, l4 = lane >> 4;
    int m0   = blockIdx.x * 16;
    int b    = wq * 16 + l15;       // this thread's batch row
    int mb   = m0 + l4 * 4;         // first of 4 consecutive m this thread owns

    // ---- one-time W panel load: slot-block sb in [0,96), kt = sb/3, g = sb%3
    for (int i = 0; i < 24; ++i) {
        int sb = wq * 24 + i;
        int kt = sb / 3, g = sb % 3;
        const unsigned short* src =
            Whh + (size_t)(g * HID + m0 + l15) * HID + kt * 32 + l4 * 8;
        gld_lds16(src, Wlds + sb * 512);
    }

    float hp[4];
    {
        float4 h4 = *(const float4*)(enc_h + (size_t)b * HID + mb);
        hp[0] = h4.x; hp[1] = h4.y; hp[2] = h4.z; hp[3] = h4.w;
    }
    float bhr[4], bhz[4], bhn[4];
    {
        float4 r4 = *(const float4*)(b_hh + mb);
        float4 z4 = *(const float4*)(b_hh + HID + mb);
        float4 n4 = *(const float4*)(b_hh + 2 * HID + mb);
        bhr[0]=r4.x; bhr[1]=r4.y; bhr[2]=r4.z; bhr[3]=r4.w;
        bhz[0]=z4.x; bhz[1]=z4.y; bhz[2]=z4.z; bhz[3]=z4.w;
        bhn[0]=n4.x; bhn[1]=n4.y; bhn[2]=n4.z; bhn[3]=n4.w;
    }
    __syncthreads();   // W panel ready (drains global_load_lds)

    for (int t = 0; t < T_STEPS; ++t) {
        const unsigned short* Asrc = (t == 0) ? h0b : (Hall + (size_t)(t - 1) * BATCH * HID);
        const unsigned long long* A8 = (const unsigned long long*)Asrc;
        size_t abase = (size_t)b * (HID / 4) + l4 * 2;   // ulong units

        // gi load (independent of h)
        const float* gib = gi + (size_t)t * BATCH * G3 + (size_t)b * G3;
        float4 giR = *(const float4*)(gib + mb);
        float4 giZ = *(const float4*)(gib + HID + mb);
        float4 giN = *(const float4*)(gib + 2 * HID + mb);
        float gr4[4] = {giR.x, giR.y, giR.z, giR.w};
        float gz4[4] = {giZ.x, giZ.y, giZ.z, giZ.w};
        float gn4[4] = {giN.x, giN.y, giN.z, giN.w};

        f32x4 acc[3];
#pragma unroll
        for (int g = 0; g < 3; ++g) acc[g] = (f32x4){0.f, 0.f, 0.f, 0.f};

#pragma unroll 8
        for (int kt = 0; kt < 32; ++kt) {
            unsigned long long lo = __hip_atomic_load(A8 + abase + (size_t)kt * 8,
                                                      __ATOMIC_RELAXED, __HIP_MEMORY_SCOPE_AGENT);
            unsigned long long hi = __hip_atomic_load(A8 + abase + (size_t)kt * 8 + 1,
                                                      __ATOMIC_RELAXED, __HIP_MEMORY_SCOPE_AGENT);
            union { unsigned long long u[2]; bf16x8 v; } hb;
            hb.u[0] = lo; hb.u[1] = hi;
#pragma unroll
            for (int g = 0; g < 3; ++g) {
                bf16x8 wfrag = *(const bf16x8*)(Wlds + ((size_t)(kt * 3 + g) * 64 + lane) * 8);
                acc[g] = __builtin_amdgcn_mfma_f32_16x16x32_bf16(wfrag, hb.v, acc[g], 0, 0, 0);
            }
        }

        // epilogue: thread owns (b, mb..mb+3)
        unsigned long long pack = 0;
#pragma unroll
        for (int j = 0; j < 4; ++j) {
            float r = 1.f / (1.f + __expf(-(gr4[j] + acc[0][j] + bhr[j])));
            float z = 1.f / (1.f + __expf(-(gz4[j] + acc[1][j] + bhz[j])));
            float e2 = __expf(2.f * (gn4[j] + r * (acc[2][j] + bhn[j])));
            float n = 1.f - 2.f / (e2 + 1.f);   // tanh
            float hnew = (1.f - z) * n + z * hp[j];
            hp[j] = hnew;
            pack |= (unsigned long long)f2bf(hnew) << (16 * j);
        }
        __hip_atomic_store((unsigned long long*)(Hall + (size_t)t * BATCH * HID +
                                                 (size_t)b * HID + mb),
                           pack, __ATOMIC_RELAXED, __HIP_MEMORY_SCOPE_AGENT);
        if (t == T_STEPS - 1) {
            float4 hf = {hp[0], hp[1], hp[2], hp[3]};
            *(float4*)(h_final + (size_t)b * HID + mb) = hf;
        }

        if (t < T_STEPS - 1) {
            __syncthreads();   // every thread's agent h-store drained (vmcnt(0) before barrier)
            if (tid == 0)
                __hip_atomic_store(flags + blockIdx.x, (unsigned)(t + 1),
                                   __ATOMIC_RELEASE, __HIP_MEMORY_SCOPE_AGENT);
            if (tid < 64) {
                while (__hip_atomic_load(flags + tid, __ATOMIC_ACQUIRE,
                                         __HIP_MEMORY_SCOPE_AGENT) < (unsigned)(t + 1))
                    __builtin_amdgcn_s_sleep(1);
            }
            __syncthreads();
        }
    }
}

// ---------------------------------------------------------------- softmax partial reduce
__global__ __launch_bounds__(64) void lsm_reduce(const float2* __restrict__ pstat,
                                                 float2* __restrict__ stats) {
    int lane = threadIdx.x;
    const float2* p = pstat + (size_t)blockIdx.x * NPART;
    float m = -1e30f;
    for (int i = lane; i < NPART; i += 64) m = fmaxf(m, p[i].x);
#pragma unroll
    for (int off = 1; off < 64; off <<= 1) m = fmaxf(m, __shfl_xor(m, off, 64));
    float s = 0.f;
    for (int i = lane; i < NPART; i += 64) { float2 t = p[i]; s += t.y * __expf(t.x - m); }
#pragma unroll
    for (int off = 1; off < 64; off <<= 1) s += __shfl_xor(s, off, 64);
    if (lane == 0) stats[blockIdx.x] = make_float2(m, logf(s));
}

// ---------------------------------------------------------------- apply: out -= mx + logZ
__global__ __launch_bounds__(256) void lsm_apply(float* __restrict__ out,
                                                 const float2* __restrict__ stats) {
    int i = blockIdx.x * 256 + threadIdx.x;
    int stride = gridDim.x * 256;
    const int total4 = ROWS * VOCABN / 4;
    for (; i < total4; i += stride) {
        int row = i / (VOCABN / 4);
        float2 st = stats[row];
        float c = st.x + st.y;
        float4 v = ((float4*)out)[i];
        v.x -= c; v.y -= c; v.z -= c; v.w -= c;
        ((float4*)out)[i] = v;
    }
}

// ----------------------------------------------------------------
extern "C" void kernel_launch(void* const* d_in, const int* in_sizes, int n_in,
                              void* d_out, int out_size, void* d_ws, size_t ws_size,
                              hipStream_t stream) {
    const float* enc_h  = (const float*)d_in[1];
    const int*   target = (const int*)d_in[2];
    const float* emb    = (const float*)d_in[3];
    const float* w_ih   = (const float*)d_in[4];
    const float* w_hh   = (const float*)d_in[5];
    const float* b_ih   = (const float*)d_in[6];
    const float* b_hh   = (const float*)d_in[7];
    const float* out_w  = (const float*)d_in[8];
    const float* out_b  = (const float*)d_in[9];
    float* out = (float*)d_out;

    char* p = (char*)d_ws;
    unsigned short* Xb   = (unsigned short*)p; p += (size_t)ROWS * HID * 2;
    unsigned short* Wih  = (unsigned short*)p; p += (size_t)G3 * HID * 2;
    unsigned short* OutW = (unsigned short*)p; p += (size_t)VOCABN * HID * 2;
    unsigned short* Hall = (unsigned short*)p; p += (size_t)ROWS * HID * 2;
    float* gi   = (float*)p; p += (size_t)ROWS * G3 * 4;
    unsigned short* Whhb = (unsigned short*)p; p += (size_t)G3 * HID * 2;
    unsigned short* h0b  = (unsigned short*)p; p += (size_t)BATCH * HID * 2;
    float2* stats = (float2*)p; p += (size_t)ROWS * 8;
    unsigned int* bar = (unsigned int*)p; p += 64 * sizeof(unsigned int);
    float2* pstat = (float2*)Xb;   // overlays Xb+Wih (dead after gi GEMM)

    f32_to_bf16<<<768, 256, 0, stream>>>(w_ih, Wih, G3 * HID / 4);
    f32_to_bf16<<<768, 256, 0, stream>>>(w_hh, Whhb, G3 * HID / 4);
    f32_to_bf16<<<2048, 256, 0, stream>>>(out_w, OutW, VOCABN * HID / 4);
    f32_to_bf16<<<64, 256, 0, stream>>>(enc_h, h0b, BATCH * HID / 4);
    embed_relu_bf16<<<ROWS, 256, 0, stream>>>(target, emb, Xb);
    init_bar<<<1, 64, 0, stream>>>(bar);

    gemm_mfma_bt<<<dim3(G3 / 128, ROWS / 128), 256, 0, stream>>>(Xb, Wih, b_ih, gi, G3, HID);

    {
        const unsigned short* a0 = h0b;
        const float* a1 = enc_h;
        const unsigned short* a2 = Whhb;
        const float* a3 = b_hh;
        const float* a4 = gi;
        unsigned short* a5 = Hall;
        float* a6 = out + OUT_HID_OFF;
        unsigned int* a7 = bar;
        void* args[] = {&a0, &a1, &a2, &a3, &a4, &a5, &a6, &a7};
        hipLaunchCooperativeKernel((void*)gru_persistent, dim3(64), dim3(256),
                                   args, 0, stream);
    }

    gemm_logits<<<dim3(NBX, NBY), 256, 0, stream>>>(Hall, OutW, out_b, out, pstat);
    lsm_reduce<<<ROWS, 64, 0, stream>>>(pstat, stats);
    lsm_apply<<<2048, 256, 0, stream>>>(out, stats);
}

// Round 7
// 747.334 us; speedup vs baseline: 1.0307x; 1.0307x over previous
//
#include <hip/hip_runtime.h>
#include <math.h>

#define T_STEPS 30
#define BATCH   64
#define HID     1024
#define VOCABN  32000
#define G3      3072
#define ROWS    (T_STEPS * BATCH)   // 1920
#define OUT_HID_OFF ((size_t)BATCH * T_STEPS * VOCABN)  // 61,440,000
#define NBY 15
#define NBX 250
#define NPART 500

typedef __attribute__((ext_vector_type(8))) short bf16x8;
typedef __attribute__((ext_vector_type(4))) float f32x4;

__device__ __forceinline__ unsigned short f2bf(float f) {
    union { float f; unsigned u; } x; x.f = f;
    unsigned r = x.u + 0x7fffu + ((x.u >> 16) & 1u);
    return (unsigned short)(r >> 16);
}

__device__ __forceinline__ void gld_lds16(const unsigned short* g, unsigned short* l) {
    __builtin_amdgcn_global_load_lds(
        (const __attribute__((address_space(1))) unsigned*)g,
        (__attribute__((address_space(3))) unsigned*)l, 16, 0, 0);
}

// ---------------------------------------------------------------- fp32 -> bf16 (RNE)
__global__ __launch_bounds__(256) void f32_to_bf16(const float* __restrict__ src,
                                                   unsigned short* __restrict__ dst, int n4) {
    int i = blockIdx.x * 256 + threadIdx.x;
    int stride = gridDim.x * 256;
    for (; i < n4; i += stride) {
        float4 v = ((const float4*)src)[i];
        ushort4 o;
        o.x = f2bf(v.x); o.y = f2bf(v.y); o.z = f2bf(v.z); o.w = f2bf(v.w);
        ((ushort4*)dst)[i] = o;
    }
}

// ---------------------------------------------------------------- X = relu(emb[tok]) -> bf16
__global__ __launch_bounds__(256) void embed_relu_bf16(const int* __restrict__ target,
                                                       const float* __restrict__ emb,
                                                       unsigned short* __restrict__ X) {
    int bid = blockIdx.x;           // t*64 + b
    int t = bid >> 6, b = bid & 63;
    int tok = (t == 0) ? 0 : target[b * T_STEPS + (t - 1)];
    const float4* src = (const float4*)(emb + (size_t)tok * HID);
    float4 v = src[threadIdx.x];
    ushort4 o;
    o.x = f2bf(fmaxf(v.x, 0.f)); o.y = f2bf(fmaxf(v.y, 0.f));
    o.z = f2bf(fmaxf(v.z, 0.f)); o.w = f2bf(fmaxf(v.w, 0.f));
    ((ushort4*)(X + (size_t)bid * HID))[threadIdx.x] = o;
}

// ---------------------------------------------------------------- barrier flags init (64 flags)
__global__ void init_bar(unsigned int* bar) {
    if (threadIdx.x < 64) bar[threadIdx.x] = 0u;
}

// ---------------------------------------------------------------- gi GEMM
__global__ __launch_bounds__(256) void gemm_mfma_bt(const unsigned short* __restrict__ A,
                                                    const unsigned short* __restrict__ W,
                                                    const float* __restrict__ bias,
                                                    float* __restrict__ out,
                                                    int N, int K) {
    __shared__ unsigned short As[128 * 64];
    __shared__ unsigned short Bs[128 * 64];
    int tid  = threadIdx.x;
    int lane = tid & 63;
    int wid  = tid >> 6;
    int wm   = wid >> 1, wn = wid & 1;
    const int bM = blockIdx.y * 128;
    const int bN = blockIdx.x * 128;

    f32x4 acc[4][4];
#pragma unroll
    for (int i = 0; i < 4; ++i)
#pragma unroll
        for (int j = 0; j < 4; ++j) acc[i][j] = (f32x4){0.f, 0.f, 0.f, 0.f};

    int sr[4], sc[4];
#pragma unroll
    for (int q = 0; q < 4; ++q) {
        sr[q] = (wid * 4 + q) * 8 + (lane >> 3);
        sc[q] = (lane & 7) ^ (sr[q] & 7);
    }

    for (int kt = 0; kt < K; kt += 64) {
        __syncthreads();
#pragma unroll
        for (int q = 0; q < 4; ++q) {
            gld_lds16(A + (size_t)(bM + sr[q]) * K + kt + sc[q] * 8, As + (wid * 4 + q) * 512);
            gld_lds16(W + (size_t)(bN + sr[q]) * K + kt + sc[q] * 8, Bs + (wid * 4 + q) * 512);
        }
        __syncthreads();

#pragma unroll
        for (int ks = 0; ks < 2; ++ks) {
            bf16x8 a[4], b[4];
#pragma unroll
            for (int mf = 0; mf < 4; ++mf) {
                int r  = wm * 64 + mf * 16 + (lane & 15);
                int ch = (ks * 4 + (lane >> 4)) ^ (r & 7);
                a[mf] = *(const bf16x8*)(As + r * 64 + ch * 8);
            }
#pragma unroll
            for (int nf = 0; nf < 4; ++nf) {
                int r  = wn * 64 + nf * 16 + (lane & 15);
                int ch = (ks * 4 + (lane >> 4)) ^ (r & 7);
                b[nf] = *(const bf16x8*)(Bs + r * 64 + ch * 8);
            }
#pragma unroll
            for (int mf = 0; mf < 4; ++mf)
#pragma unroll
                for (int nf = 0; nf < 4; ++nf)
                    acc[mf][nf] = __builtin_amdgcn_mfma_f32_16x16x32_bf16(
                        a[mf], b[nf], acc[mf][nf], 0, 0, 0);
        }
    }

    int rif = (lane >> 4) * 4;
    int col = lane & 15;
#pragma unroll
    for (int mf = 0; mf < 4; ++mf) {
#pragma unroll
        for (int j = 0; j < 4; ++j) {
            int gr = bM + wm * 64 + mf * 16 + rif + j;
#pragma unroll
            for (int nf = 0; nf < 4; ++nf) {
                int gc = bN + wn * 64 + nf * 16 + col;
                out[(size_t)gr * N + gc] = acc[mf][nf][j] + bias[gc];
            }
        }
    }
}

// ---------------------------------------------------------------- logits GEMM + permute + softmax partials
__global__ __launch_bounds__(256) void gemm_logits(const unsigned short* __restrict__ A,
                                                   const unsigned short* __restrict__ W,
                                                   const float* __restrict__ bias,
                                                   float* __restrict__ out,
                                                   float2* __restrict__ pstat) {
    __shared__ unsigned short As[128 * 64];
    __shared__ unsigned short Bs[128 * 64];
    int bx = blockIdx.x;
    int by = blockIdx.y;
    const int bM = by * 128;
    const int bN = bx * 128;
    const int K = HID;

    int tid  = threadIdx.x;
    int lane = tid & 63;
    int wid  = tid >> 6;
    int wm   = wid >> 1, wn = wid & 1;

    f32x4 acc[4][4];
#pragma unroll
    for (int i = 0; i < 4; ++i)
#pragma unroll
        for (int j = 0; j < 4; ++j) acc[i][j] = (f32x4){0.f, 0.f, 0.f, 0.f};

    int sr[4], sc[4];
#pragma unroll
    for (int q = 0; q < 4; ++q) {
        sr[q] = (wid * 4 + q) * 8 + (lane >> 3);
        sc[q] = (lane & 7) ^ (sr[q] & 7);
    }

    for (int kt = 0; kt < K; kt += 64) {
        __syncthreads();
#pragma unroll
        for (int q = 0; q < 4; ++q) {
            gld_lds16(A + (size_t)(bM + sr[q]) * K + kt + sc[q] * 8, As + (wid * 4 + q) * 512);
            gld_lds16(W + (size_t)(bN + sr[q]) * K + kt + sc[q] * 8, Bs + (wid * 4 + q) * 512);
        }
        __syncthreads();

#pragma unroll
        for (int ks = 0; ks < 2; ++ks) {
            bf16x8 a[4], b[4];
#pragma unroll
            for (int mf = 0; mf < 4; ++mf) {
                int r  = wm * 64 + mf * 16 + (lane & 15);
                int ch = (ks * 4 + (lane >> 4)) ^ (r & 7);
                a[mf] = *(const bf16x8*)(As + r * 64 + ch * 8);
            }
#pragma unroll
            for (int nf = 0; nf < 4; ++nf) {
                int r  = wn * 64 + nf * 16 + (lane & 15);
                int ch = (ks * 4 + (lane >> 4)) ^ (r & 7);
                b[nf] = *(const bf16x8*)(Bs + r * 64 + ch * 8);
            }
#pragma unroll
            for (int mf = 0; mf < 4; ++mf)
#pragma unroll
                for (int nf = 0; nf < 4; ++nf)
                    acc[mf][nf] = __builtin_amdgcn_mfma_f32_16x16x32_bf16(
                        a[mf], b[nf], acc[mf][nf], 0, 0, 0);
        }
    }

    int rif = (lane >> 4) * 4;
    int col = lane & 15;
#pragma unroll
    for (int mf = 0; mf < 4; ++mf) {
#pragma unroll
        for (int j = 0; j < 4; ++j) {
            int gr = bM + wm * 64 + mf * 16 + rif + j;
            int t = gr >> 6, b = gr & 63;
            int prow = b * T_STEPS + t;
            float v[4];
            float mx = -1e30f;
#pragma unroll
            for (int nf = 0; nf < 4; ++nf) {
                int gc = bN + wn * 64 + nf * 16 + col;
                v[nf] = acc[mf][nf][j] + bias[gc];
                out[(size_t)prow * VOCABN + gc] = v[nf];
                mx = fmaxf(mx, v[nf]);
            }
#pragma unroll
            for (int off = 1; off < 16; off <<= 1) mx = fmaxf(mx, __shfl_xor(mx, off, 64));
            float se = 0.f;
#pragma unroll
            for (int nf = 0; nf < 4; ++nf) se += __expf(v[nf] - mx);
#pragma unroll
            for (int off = 1; off < 16; off <<= 1) se += __shfl_xor(se, off, 64);
            if (col == 0) pstat[(size_t)prow * NPART + bx * 2 + wn] = make_float2(mx, se);
        }
    }
}

// ---------------------------------------------------------------- persistent 30-step GRU
// 64 blocks x 256 threads (cooperative). Block owns m in [bid*16, bid*16+16).
// W panel LDS-resident. ALL inter-block traffic (h data + flags) via sc1
// relaxed atomics ONLY -- zero acquire/release in the step loop, so no
// buffer_inv / buffer_wbl2 L2 maintenance ops (the round-4/5/6 cost).
// Ordering: producer __syncthreads drains vmcnt(0) (h-stores ACKed at the
// coherence point) before tid0's relaxed flag store; consumer's h loads are
// control-dependent on the polled flag value (+ sched_barrier vs compiler).
__global__ __launch_bounds__(256) void gru_persistent(
    const unsigned short* __restrict__ h0b,   // [64][1024] bf16
    const float* __restrict__ enc_h,          // [64][1024] fp32
    const unsigned short* __restrict__ Whh,   // [3072][1024] bf16
    const float* __restrict__ b_hh,
    const float* __restrict__ gi,             // [30][64][3072] fp32
    unsigned short* __restrict__ Hall,        // [30][64][1024] bf16
    float* __restrict__ h_final,              // [64][1024] fp32
    unsigned int* __restrict__ flags)         // [64] zeroed per launch
{
    __shared__ unsigned short Wlds[48 * 1024];   // 96 KB: slot[(kt*3+g)*64 + lane] = 8 bf16
    int tid  = threadIdx.x;
    int lane = tid & 63;
    int wq   = tid >> 6;            // batch quarter
    int l15  = lane & 15, l4 = lane >> 4;
    int m0   = blockIdx.x * 16;
    int b    = wq * 16 + l15;       // this thread's batch row
    int mb   = m0 + l4 * 4;         // first of 4 consecutive m this thread owns

    // ---- one-time W panel load: slot-block sb in [0,96), kt = sb/3, g = sb%3
    for (int i = 0; i < 24; ++i) {
        int sb = wq * 24 + i;
        int kt = sb / 3, g = sb % 3;
        const unsigned short* src =
            Whh + (size_t)(g * HID + m0 + l15) * HID + kt * 32 + l4 * 8;
        gld_lds16(src, Wlds + sb * 512);
    }

    float hp[4];
    {
        float4 h4 = *(const float4*)(enc_h + (size_t)b * HID + mb);
        hp[0] = h4.x; hp[1] = h4.y; hp[2] = h4.z; hp[3] = h4.w;
    }
    float bhr[4], bhz[4], bhn[4];
    {
        float4 r4 = *(const float4*)(b_hh + mb);
        float4 z4 = *(const float4*)(b_hh + HID + mb);
        float4 n4 = *(const float4*)(b_hh + 2 * HID + mb);
        bhr[0]=r4.x; bhr[1]=r4.y; bhr[2]=r4.z; bhr[3]=r4.w;
        bhz[0]=z4.x; bhz[1]=z4.y; bhz[2]=z4.z; bhz[3]=z4.w;
        bhn[0]=n4.x; bhn[1]=n4.y; bhn[2]=n4.z; bhn[3]=n4.w;
    }
    __syncthreads();   // W panel ready (drains global_load_lds)

    for (int t = 0; t < T_STEPS; ++t) {
        const unsigned short* Asrc = (t == 0) ? h0b : (Hall + (size_t)(t - 1) * BATCH * HID);
        const unsigned long long* A8 = (const unsigned long long*)Asrc;
        size_t abase = (size_t)b * (HID / 4) + l4 * 2;   // ulong units

        // gi load (independent of h)
        const float* gib = gi + (size_t)t * BATCH * G3 + (size_t)b * G3;
        float4 giR = *(const float4*)(gib + mb);
        float4 giZ = *(const float4*)(gib + HID + mb);
        float4 giN = *(const float4*)(gib + 2 * HID + mb);
        float gr4[4] = {giR.x, giR.y, giR.z, giR.w};
        float gz4[4] = {giZ.x, giZ.y, giZ.z, giZ.w};
        float gn4[4] = {giN.x, giN.y, giN.z, giN.w};

        f32x4 acc[3];
#pragma unroll
        for (int g = 0; g < 3; ++g) acc[g] = (f32x4){0.f, 0.f, 0.f, 0.f};

#pragma unroll 8
        for (int kt = 0; kt < 32; ++kt) {
            unsigned long long lo = __hip_atomic_load(A8 + abase + (size_t)kt * 8,
                                                      __ATOMIC_RELAXED, __HIP_MEMORY_SCOPE_AGENT);
            unsigned long long hi = __hip_atomic_load(A8 + abase + (size_t)kt * 8 + 1,
                                                      __ATOMIC_RELAXED, __HIP_MEMORY_SCOPE_AGENT);
            union { unsigned long long u[2]; bf16x8 v; } hb;
            hb.u[0] = lo; hb.u[1] = hi;
#pragma unroll
            for (int g = 0; g < 3; ++g) {
                bf16x8 wfrag = *(const bf16x8*)(Wlds + ((size_t)(kt * 3 + g) * 64 + lane) * 8);
                acc[g] = __builtin_amdgcn_mfma_f32_16x16x32_bf16(wfrag, hb.v, acc[g], 0, 0, 0);
            }
        }

        // epilogue: thread owns (b, mb..mb+3)
        unsigned long long pack = 0;
#pragma unroll
        for (int j = 0; j < 4; ++j) {
            float r = 1.f / (1.f + __expf(-(gr4[j] + acc[0][j] + bhr[j])));
            float z = 1.f / (1.f + __expf(-(gz4[j] + acc[1][j] + bhz[j])));
            float e2 = __expf(2.f * (gn4[j] + r * (acc[2][j] + bhn[j])));
            float n = 1.f - 2.f / (e2 + 1.f);   // tanh
            float hnew = (1.f - z) * n + z * hp[j];
            hp[j] = hnew;
            pack |= (unsigned long long)f2bf(hnew) << (16 * j);
        }
        __hip_atomic_store((unsigned long long*)(Hall + (size_t)t * BATCH * HID +
                                                 (size_t)b * HID + mb),
                           pack, __ATOMIC_RELAXED, __HIP_MEMORY_SCOPE_AGENT);
        if (t == T_STEPS - 1) {
            float4 hf = {hp[0], hp[1], hp[2], hp[3]};
            *(float4*)(h_final + (size_t)b * HID + mb) = hf;
        }

        if (t < T_STEPS - 1) {
            __syncthreads();   // compiler: s_waitcnt vmcnt(0) before s_barrier ->
                               // every wave's sc1 h-store ACKed at coherence point
            if (tid == 0)
                __hip_atomic_store(flags + blockIdx.x, (unsigned)(t + 1),
                                   __ATOMIC_RELAXED, __HIP_MEMORY_SCOPE_AGENT);
            if (tid < 64) {
                while (__hip_atomic_load(flags + tid, __ATOMIC_RELAXED,
                                         __HIP_MEMORY_SCOPE_AGENT) < (unsigned)(t + 1))
                    __builtin_amdgcn_s_sleep(1);
            }
            __builtin_amdgcn_sched_barrier(0);   // no compiler motion past the poll
            __syncthreads();
        }
    }
}

// ---------------------------------------------------------------- softmax partial reduce
__global__ __launch_bounds__(64) void lsm_reduce(const float2* __restrict__ pstat,
                                                 float2* __restrict__ stats) {
    int lane = threadIdx.x;
    const float2* p = pstat + (size_t)blockIdx.x * NPART;
    float m = -1e30f;
    for (int i = lane; i < NPART; i += 64) m = fmaxf(m, p[i].x);
#pragma unroll
    for (int off = 1; off < 64; off <<= 1) m = fmaxf(m, __shfl_xor(m, off, 64));
    float s = 0.f;
    for (int i = lane; i < NPART; i += 64) { float2 t = p[i]; s += t.y * __expf(t.x - m); }
#pragma unroll
    for (int off = 1; off < 64; off <<= 1) s += __shfl_xor(s, off, 64);
    if (lane == 0) stats[blockIdx.x] = make_float2(m, logf(s));
}

// ---------------------------------------------------------------- apply: out -= mx + logZ
__global__ __launch_bounds__(256) void lsm_apply(float* __restrict__ out,
                                                 const float2* __restrict__ stats) {
    int i = blockIdx.x * 256 + threadIdx.x;
    int stride = gridDim.x * 256;
    const int total4 = ROWS * VOCABN / 4;
    for (; i < total4; i += stride) {
        int row = i / (VOCABN / 4);
        float2 st = stats[row];
        float c = st.x + st.y;
        float4 v = ((float4*)out)[i];
        v.x -= c; v.y -= c; v.z -= c; v.w -= c;
        ((float4*)out)[i] = v;
    }
}

// ----------------------------------------------------------------
extern "C" void kernel_launch(void* const* d_in, const int* in_sizes, int n_in,
                              void* d_out, int out_size, void* d_ws, size_t ws_size,
                              hipStream_t stream) {
    const float* enc_h  = (const float*)d_in[1];
    const int*   target = (const int*)d_in[2];
    const float* emb    = (const float*)d_in[3];
    const float* w_ih   = (const float*)d_in[4];
    const float* w_hh   = (const float*)d_in[5];
    const float* b_ih   = (const float*)d_in[6];
    const float* b_hh   = (const float*)d_in[7];
    const float* out_w  = (const float*)d_in[8];
    const float* out_b  = (const float*)d_in[9];
    float* out = (float*)d_out;

    char* p = (char*)d_ws;
    unsigned short* Xb   = (unsigned short*)p; p += (size_t)ROWS * HID * 2;
    unsigned short* Wih  = (unsigned short*)p; p += (size_t)G3 * HID * 2;
    unsigned short* OutW = (unsigned short*)p; p += (size_t)VOCABN * HID * 2;
    unsigned short* Hall = (unsigned short*)p; p += (size_t)ROWS * HID * 2;
    float* gi   = (float*)p; p += (size_t)ROWS * G3 * 4;
    unsigned short* Whhb = (unsigned short*)p; p += (size_t)G3 * HID * 2;
    unsigned short* h0b  = (unsigned short*)p; p += (size_t)BATCH * HID * 2;
    float2* stats = (float2*)p; p += (size_t)ROWS * 8;
    unsigned int* bar = (unsigned int*)p; p += 64 * sizeof(unsigned int);
    float2* pstat = (float2*)Xb;   // overlays Xb+Wih (dead after gi GEMM)

    f32_to_bf16<<<768, 256, 0, stream>>>(w_ih, Wih, G3 * HID / 4);
    f32_to_bf16<<<768, 256, 0, stream>>>(w_hh, Whhb, G3 * HID / 4);
    f32_to_bf16<<<2048, 256, 0, stream>>>(out_w, OutW, VOCABN * HID / 4);
    f32_to_bf16<<<64, 256, 0, stream>>>(enc_h, h0b, BATCH * HID / 4);
    embed_relu_bf16<<<ROWS, 256, 0, stream>>>(target, emb, Xb);
    init_bar<<<1, 64, 0, stream>>>(bar);

    gemm_mfma_bt<<<dim3(G3 / 128, ROWS / 128), 256, 0, stream>>>(Xb, Wih, b_ih, gi, G3, HID);

    {
        const unsigned short* a0 = h0b;
        const float* a1 = enc_h;
        const unsigned short* a2 = Whhb;
        const float* a3 = b_hh;
        const float* a4 = gi;
        unsigned short* a5 = Hall;
        float* a6 = out + OUT_HID_OFF;
        unsigned int* a7 = bar;
        void* args[] = {&a0, &a1, &a2, &a3, &a4, &a5, &a6, &a7};
        hipLaunchCooperativeKernel((void*)gru_persistent, dim3(64), dim3(256),
                                   args, 0, stream);
    }

    gemm_logits<<<dim3(NBX, NBY), 256, 0, stream>>>(Hall, OutW, out_b, out, pstat);
    lsm_reduce<<<ROWS, 64, 0, stream>>>(pstat, stats);
    lsm_apply<<<2048, 256, 0, stream>>>(out, stats);
}

// Round 8
// 593.270 us; speedup vs baseline: 1.2984x; 1.2597x over previous
//
#include <hip/hip_runtime.h>
#include <math.h>

#define T_STEPS 30
#define BATCH   64
#define HID     1024
#define VOCABN  32000
#define G3      3072
#define ROWS    (T_STEPS * BATCH)   // 1920
#define OUT_HID_OFF ((size_t)BATCH * T_STEPS * VOCABN)  // 61,440,000
#define NBY 15
#define NBX 250
#define NPART 500

typedef __attribute__((ext_vector_type(8))) short bf16x8;
typedef __attribute__((ext_vector_type(4))) float f32x4;

__device__ __forceinline__ unsigned short f2bf(float f) {
    union { float f; unsigned u; } x; x.f = f;
    unsigned r = x.u + 0x7fffu + ((x.u >> 16) & 1u);
    return (unsigned short)(r >> 16);
}

__device__ __forceinline__ void gld_lds16(const unsigned short* g, unsigned short* l) {
    __builtin_amdgcn_global_load_lds(
        (const __attribute__((address_space(1))) unsigned*)g,
        (__attribute__((address_space(3))) unsigned*)l, 16, 0, 0);
}

// ---------------------------------------------------------------- fp32 -> bf16 (RNE)
__global__ __launch_bounds__(256) void f32_to_bf16(const float* __restrict__ src,
                                                   unsigned short* __restrict__ dst, int n4) {
    int i = blockIdx.x * 256 + threadIdx.x;
    int stride = gridDim.x * 256;
    for (; i < n4; i += stride) {
        float4 v = ((const float4*)src)[i];
        ushort4 o;
        o.x = f2bf(v.x); o.y = f2bf(v.y); o.z = f2bf(v.z); o.w = f2bf(v.w);
        ((ushort4*)dst)[i] = o;
    }
}

// ---------------------------------------------------------------- X = relu(emb[tok]) -> bf16
__global__ __launch_bounds__(256) void embed_relu_bf16(const int* __restrict__ target,
                                                       const float* __restrict__ emb,
                                                       unsigned short* __restrict__ X) {
    int bid = blockIdx.x;           // t*64 + b
    int t = bid >> 6, b = bid & 63;
    int tok = (t == 0) ? 0 : target[b * T_STEPS + (t - 1)];
    const float4* src = (const float4*)(emb + (size_t)tok * HID);
    float4 v = src[threadIdx.x];
    ushort4 o;
    o.x = f2bf(fmaxf(v.x, 0.f)); o.y = f2bf(fmaxf(v.y, 0.f));
    o.z = f2bf(fmaxf(v.z, 0.f)); o.w = f2bf(fmaxf(v.w, 0.f));
    ((ushort4*)(X + (size_t)bid * HID))[threadIdx.x] = o;
}

// ---------------------------------------------------------------- barrier flags init (64 flags)
__global__ void init_bar(unsigned int* bar) {
    if (threadIdx.x < 64) bar[threadIdx.x] = 0u;
}

// ---------------------------------------------------------------- gi GEMM
__global__ __launch_bounds__(256) void gemm_mfma_bt(const unsigned short* __restrict__ A,
                                                    const unsigned short* __restrict__ W,
                                                    const float* __restrict__ bias,
                                                    float* __restrict__ out,
                                                    int N, int K) {
    __shared__ unsigned short As[128 * 64];
    __shared__ unsigned short Bs[128 * 64];
    int tid  = threadIdx.x;
    int lane = tid & 63;
    int wid  = tid >> 6;
    int wm   = wid >> 1, wn = wid & 1;
    const int bM = blockIdx.y * 128;
    const int bN = blockIdx.x * 128;

    f32x4 acc[4][4];
#pragma unroll
    for (int i = 0; i < 4; ++i)
#pragma unroll
        for (int j = 0; j < 4; ++j) acc[i][j] = (f32x4){0.f, 0.f, 0.f, 0.f};

    int sr[4], sc[4];
#pragma unroll
    for (int q = 0; q < 4; ++q) {
        sr[q] = (wid * 4 + q) * 8 + (lane >> 3);
        sc[q] = (lane & 7) ^ (sr[q] & 7);
    }

    for (int kt = 0; kt < K; kt += 64) {
        __syncthreads();
#pragma unroll
        for (int q = 0; q < 4; ++q) {
            gld_lds16(A + (size_t)(bM + sr[q]) * K + kt + sc[q] * 8, As + (wid * 4 + q) * 512);
            gld_lds16(W + (size_t)(bN + sr[q]) * K + kt + sc[q] * 8, Bs + (wid * 4 + q) * 512);
        }
        __syncthreads();

#pragma unroll
        for (int ks = 0; ks < 2; ++ks) {
            bf16x8 a[4], b[4];
#pragma unroll
            for (int mf = 0; mf < 4; ++mf) {
                int r  = wm * 64 + mf * 16 + (lane & 15);
                int ch = (ks * 4 + (lane >> 4)) ^ (r & 7);
                a[mf] = *(const bf16x8*)(As + r * 64 + ch * 8);
            }
#pragma unroll
            for (int nf = 0; nf < 4; ++nf) {
                int r  = wn * 64 + nf * 16 + (lane & 15);
                int ch = (ks * 4 + (lane >> 4)) ^ (r & 7);
                b[nf] = *(const bf16x8*)(Bs + r * 64 + ch * 8);
            }
#pragma unroll
            for (int mf = 0; mf < 4; ++mf)
#pragma unroll
                for (int nf = 0; nf < 4; ++nf)
                    acc[mf][nf] = __builtin_amdgcn_mfma_f32_16x16x32_bf16(
                        a[mf], b[nf], acc[mf][nf], 0, 0, 0);
        }
    }

    int rif = (lane >> 4) * 4;
    int col = lane & 15;
#pragma unroll
    for (int mf = 0; mf < 4; ++mf) {
#pragma unroll
        for (int j = 0; j < 4; ++j) {
            int gr = bM + wm * 64 + mf * 16 + rif + j;
#pragma unroll
            for (int nf = 0; nf < 4; ++nf) {
                int gc = bN + wn * 64 + nf * 16 + col;
                out[(size_t)gr * N + gc] = acc[mf][nf][j] + bias[gc];
            }
        }
    }
}

// ---------------------------------------------------------------- logits GEMM + permute + softmax partials
__global__ __launch_bounds__(256) void gemm_logits(const unsigned short* __restrict__ A,
                                                   const unsigned short* __restrict__ W,
                                                   const float* __restrict__ bias,
                                                   float* __restrict__ out,
                                                   float2* __restrict__ pstat) {
    __shared__ unsigned short As[128 * 64];
    __shared__ unsigned short Bs[128 * 64];
    int bx = blockIdx.x;
    int by = blockIdx.y;
    const int bM = by * 128;
    const int bN = bx * 128;
    const int K = HID;

    int tid  = threadIdx.x;
    int lane = tid & 63;
    int wid  = tid >> 6;
    int wm   = wid >> 1, wn = wid & 1;

    f32x4 acc[4][4];
#pragma unroll
    for (int i = 0; i < 4; ++i)
#pragma unroll
        for (int j = 0; j < 4; ++j) acc[i][j] = (f32x4){0.f, 0.f, 0.f, 0.f};

    int sr[4], sc[4];
#pragma unroll
    for (int q = 0; q < 4; ++q) {
        sr[q] = (wid * 4 + q) * 8 + (lane >> 3);
        sc[q] = (lane & 7) ^ (sr[q] & 7);
    }

    for (int kt = 0; kt < K; kt += 64) {
        __syncthreads();
#pragma unroll
        for (int q = 0; q < 4; ++q) {
            gld_lds16(A + (size_t)(bM + sr[q]) * K + kt + sc[q] * 8, As + (wid * 4 + q) * 512);
            gld_lds16(W + (size_t)(bN + sr[q]) * K + kt + sc[q] * 8, Bs + (wid * 4 + q) * 512);
        }
        __syncthreads();

#pragma unroll
        for (int ks = 0; ks < 2; ++ks) {
            bf16x8 a[4], b[4];
#pragma unroll
            for (int mf = 0; mf < 4; ++mf) {
                int r  = wm * 64 + mf * 16 + (lane & 15);
                int ch = (ks * 4 + (lane >> 4)) ^ (r & 7);
                a[mf] = *(const bf16x8*)(As + r * 64 + ch * 8);
            }
#pragma unroll
            for (int nf = 0; nf < 4; ++nf) {
                int r  = wn * 64 + nf * 16 + (lane & 15);
                int ch = (ks * 4 + (lane >> 4)) ^ (r & 7);
                b[nf] = *(const bf16x8*)(Bs + r * 64 + ch * 8);
            }
#pragma unroll
            for (int mf = 0; mf < 4; ++mf)
#pragma unroll
                for (int nf = 0; nf < 4; ++nf)
                    acc[mf][nf] = __builtin_amdgcn_mfma_f32_16x16x32_bf16(
                        a[mf], b[nf], acc[mf][nf], 0, 0, 0);
        }
    }

    int rif = (lane >> 4) * 4;
    int col = lane & 15;
#pragma unroll
    for (int mf = 0; mf < 4; ++mf) {
#pragma unroll
        for (int j = 0; j < 4; ++j) {
            int gr = bM + wm * 64 + mf * 16 + rif + j;
            int t = gr >> 6, b = gr & 63;
            int prow = b * T_STEPS + t;
            float v[4];
            float mx = -1e30f;
#pragma unroll
            for (int nf = 0; nf < 4; ++nf) {
                int gc = bN + wn * 64 + nf * 16 + col;
                v[nf] = acc[mf][nf][j] + bias[gc];
                out[(size_t)prow * VOCABN + gc] = v[nf];
                mx = fmaxf(mx, v[nf]);
            }
#pragma unroll
            for (int off = 1; off < 16; off <<= 1) mx = fmaxf(mx, __shfl_xor(mx, off, 64));
            float se = 0.f;
#pragma unroll
            for (int nf = 0; nf < 4; ++nf) se += __expf(v[nf] - mx);
#pragma unroll
            for (int off = 1; off < 16; off <<= 1) se += __shfl_xor(se, off, 64);
            if (col == 0) pstat[(size_t)prow * NPART + bx * 2 + wn] = make_float2(mx, se);
        }
    }
}

// ---------------------------------------------------------------- persistent 30-step GRU
// 64 blocks x 256 threads (cooperative), 1 block/CU -> VGPRs are free.
// Block owns m in [bid*16, bid*16+16). W panel LDS-resident.
// Producer side: h stored via sc1 relaxed atomics (write-through to LLC),
// vmcnt-drained by __syncthreads, then tid0's relaxed sc1 flag store.
// Consumer side: poll flags (relaxed sc1), then PLAIN vectorized h loads:
// correct because each Hall[t] region is single-touch per dispatch (no
// cached pre-store copy can exist; dispatch-start invalidate clears replays),
// and all 32 16B loads are issued before the MFMA loop (one latency exposure).
__global__ __launch_bounds__(256, 1) void gru_persistent(
    const unsigned short* __restrict__ h0b,   // [64][1024] bf16
    const float* __restrict__ enc_h,          // [64][1024] fp32
    const unsigned short* __restrict__ Whh,   // [3072][1024] bf16
    const float* __restrict__ b_hh,
    const float* __restrict__ gi,             // [30][64][3072] fp32
    unsigned short* __restrict__ Hall,        // [30][64][1024] bf16
    float* __restrict__ h_final,              // [64][1024] fp32
    unsigned int* __restrict__ flags)         // [64] zeroed per launch
{
    __shared__ unsigned short Wlds[48 * 1024];   // 96 KB: slot[(kt*3+g)*64 + lane] = 8 bf16
    int tid  = threadIdx.x;
    int lane = tid & 63;
    int wq   = tid >> 6;            // batch quarter
    int l15  = lane & 15, l4 = lane >> 4;
    int m0   = blockIdx.x * 16;
    int b    = wq * 16 + l15;       // this thread's batch row
    int mb   = m0 + l4 * 4;         // first of 4 consecutive m this thread owns

    // ---- one-time W panel load: slot-block sb in [0,96), kt = sb/3, g = sb%3
    for (int i = 0; i < 24; ++i) {
        int sb = wq * 24 + i;
        int kt = sb / 3, g = sb % 3;
        const unsigned short* src =
            Whh + (size_t)(g * HID + m0 + l15) * HID + kt * 32 + l4 * 8;
        gld_lds16(src, Wlds + sb * 512);
    }

    float hp[4];
    {
        float4 h4 = *(const float4*)(enc_h + (size_t)b * HID + mb);
        hp[0] = h4.x; hp[1] = h4.y; hp[2] = h4.z; hp[3] = h4.w;
    }
    float bhr[4], bhz[4], bhn[4];
    {
        float4 r4 = *(const float4*)(b_hh + mb);
        float4 z4 = *(const float4*)(b_hh + HID + mb);
        float4 n4 = *(const float4*)(b_hh + 2 * HID + mb);
        bhr[0]=r4.x; bhr[1]=r4.y; bhr[2]=r4.z; bhr[3]=r4.w;
        bhz[0]=z4.x; bhz[1]=z4.y; bhz[2]=z4.z; bhz[3]=z4.w;
        bhn[0]=n4.x; bhn[1]=n4.y; bhn[2]=n4.z; bhn[3]=n4.w;
    }
    __syncthreads();   // W panel ready (drains global_load_lds)

    int arow16 = b * 128 + l4;      // thread's h-row base in 16B units (+ kt*4)

    for (int t = 0; t < T_STEPS; ++t) {
        // ---- gi[t] loads: flag-independent, issued BEFORE the poll to
        // overlap the wait (plain loads, L2/LLC).
        const float* gib = gi + (size_t)t * BATCH * G3 + (size_t)b * G3;
        float4 giR = *(const float4*)(gib + mb);
        float4 giZ = *(const float4*)(gib + HID + mb);
        float4 giN = *(const float4*)(gib + 2 * HID + mb);
        float gr4[4] = {giR.x, giR.y, giR.z, giR.w};
        float gz4[4] = {giZ.x, giZ.y, giZ.z, giZ.w};
        float gn4[4] = {giN.x, giN.y, giN.z, giN.w};

        if (t > 0) {
            if (tid < 64) {
                while (__hip_atomic_load(flags + tid, __ATOMIC_RELAXED,
                                         __HIP_MEMORY_SCOPE_AGENT) < (unsigned)t) {}
            }
            __builtin_amdgcn_sched_barrier(0);
            __syncthreads();
            asm volatile("" ::: "memory");   // no IR-level load hoisting above the poll
        }

        const unsigned short* Asrc = (t == 0) ? h0b : (Hall + (size_t)(t - 1) * BATCH * HID);
        const bf16x8* A16 = (const bf16x8*)Asrc;

        // ---- issue ALL 32 h-chunk loads (plain dwordx4), then consume
        bf16x8 hreg[32];
#pragma unroll
        for (int kt = 0; kt < 32; ++kt) hreg[kt] = A16[arow16 + kt * 4];

        f32x4 acc[3];
#pragma unroll
        for (int g = 0; g < 3; ++g) acc[g] = (f32x4){0.f, 0.f, 0.f, 0.f};

#pragma unroll
        for (int kt = 0; kt < 32; ++kt) {
#pragma unroll
            for (int g = 0; g < 3; ++g) {
                bf16x8 wfrag = *(const bf16x8*)(Wlds + ((size_t)(kt * 3 + g) * 64 + lane) * 8);
                acc[g] = __builtin_amdgcn_mfma_f32_16x16x32_bf16(wfrag, hreg[kt], acc[g], 0, 0, 0);
            }
        }

        // ---- epilogue: thread owns (b, mb..mb+3)
        unsigned long long pack = 0;
#pragma unroll
        for (int j = 0; j < 4; ++j) {
            float r = 1.f / (1.f + __expf(-(gr4[j] + acc[0][j] + bhr[j])));
            float z = 1.f / (1.f + __expf(-(gz4[j] + acc[1][j] + bhz[j])));
            float e2 = __expf(2.f * (gn4[j] + r * (acc[2][j] + bhn[j])));
            float n = 1.f - 2.f / (e2 + 1.f);   // tanh
            float hnew = (1.f - z) * n + z * hp[j];
            hp[j] = hnew;
            pack |= (unsigned long long)f2bf(hnew) << (16 * j);
        }
        __hip_atomic_store((unsigned long long*)(Hall + (size_t)t * BATCH * HID +
                                                 (size_t)b * HID + mb),
                           pack, __ATOMIC_RELAXED, __HIP_MEMORY_SCOPE_AGENT);
        if (t == T_STEPS - 1) {
            float4 hf = {hp[0], hp[1], hp[2], hp[3]};
            *(float4*)(h_final + (size_t)b * HID + mb) = hf;
        }

        if (t < T_STEPS - 1) {
            __syncthreads();   // s_waitcnt vmcnt(0) -> all waves' sc1 h-stores ACKed at LLC
            if (tid == 0)
                __hip_atomic_store(flags + blockIdx.x, (unsigned)(t + 1),
                                   __ATOMIC_RELAXED, __HIP_MEMORY_SCOPE_AGENT);
        }
    }
}

// ---------------------------------------------------------------- softmax partial reduce
__global__ __launch_bounds__(64) void lsm_reduce(const float2* __restrict__ pstat,
                                                 float2* __restrict__ stats) {
    int lane = threadIdx.x;
    const float2* p = pstat + (size_t)blockIdx.x * NPART;
    float m = -1e30f;
    for (int i = lane; i < NPART; i += 64) m = fmaxf(m, p[i].x);
#pragma unroll
    for (int off = 1; off < 64; off <<= 1) m = fmaxf(m, __shfl_xor(m, off, 64));
    float s = 0.f;
    for (int i = lane; i < NPART; i += 64) { float2 t = p[i]; s += t.y * __expf(t.x - m); }
#pragma unroll
    for (int off = 1; off < 64; off <<= 1) s += __shfl_xor(s, off, 64);
    if (lane == 0) stats[blockIdx.x] = make_float2(m, logf(s));
}

// ---------------------------------------------------------------- apply: out -= mx + logZ
__global__ __launch_bounds__(256) void lsm_apply(float* __restrict__ out,
                                                 const float2* __restrict__ stats) {
    int i = blockIdx.x * 256 + threadIdx.x;
    int stride = gridDim.x * 256;
    const int total4 = ROWS * VOCABN / 4;
    for (; i < total4; i += stride) {
        int row = i / (VOCABN / 4);
        float2 st = stats[row];
        float c = st.x + st.y;
        float4 v = ((float4*)out)[i];
        v.x -= c; v.y -= c; v.z -= c; v.w -= c;
        ((float4*)out)[i] = v;
    }
}

// ----------------------------------------------------------------
extern "C" void kernel_launch(void* const* d_in, const int* in_sizes, int n_in,
                              void* d_out, int out_size, void* d_ws, size_t ws_size,
                              hipStream_t stream) {
    const float* enc_h  = (const float*)d_in[1];
    const int*   target = (const int*)d_in[2];
    const float* emb    = (const float*)d_in[3];
    const float* w_ih   = (const float*)d_in[4];
    const float* w_hh   = (const float*)d_in[5];
    const float* b_ih   = (const float*)d_in[6];
    const float* b_hh   = (const float*)d_in[7];
    const float* out_w  = (const float*)d_in[8];
    const float* out_b  = (const float*)d_in[9];
    float* out = (float*)d_out;

    char* p = (char*)d_ws;
    unsigned short* Xb   = (unsigned short*)p; p += (size_t)ROWS * HID * 2;
    unsigned short* Wih  = (unsigned short*)p; p += (size_t)G3 * HID * 2;
    unsigned short* OutW = (unsigned short*)p; p += (size_t)VOCABN * HID * 2;
    unsigned short* Hall = (unsigned short*)p; p += (size_t)ROWS * HID * 2;
    float* gi   = (float*)p; p += (size_t)ROWS * G3 * 4;
    unsigned short* Whhb = (unsigned short*)p; p += (size_t)G3 * HID * 2;
    unsigned short* h0b  = (unsigned short*)p; p += (size_t)BATCH * HID * 2;
    float2* stats = (float2*)p; p += (size_t)ROWS * 8;
    unsigned int* bar = (unsigned int*)p; p += 64 * sizeof(unsigned int);
    float2* pstat = (float2*)Xb;   // overlays Xb+Wih (dead after gi GEMM)

    f32_to_bf16<<<768, 256, 0, stream>>>(w_ih, Wih, G3 * HID / 4);
    f32_to_bf16<<<768, 256, 0, stream>>>(w_hh, Whhb, G3 * HID / 4);
    f32_to_bf16<<<2048, 256, 0, stream>>>(out_w, OutW, VOCABN * HID / 4);
    f32_to_bf16<<<64, 256, 0, stream>>>(enc_h, h0b, BATCH * HID / 4);
    embed_relu_bf16<<<ROWS, 256, 0, stream>>>(target, emb, Xb);
    init_bar<<<1, 64, 0, stream>>>(bar);

    gemm_mfma_bt<<<dim3(G3 / 128, ROWS / 128), 256, 0, stream>>>(Xb, Wih, b_ih, gi, G3, HID);

    {
        const unsigned short* a0 = h0b;
        const float* a1 = enc_h;
        const unsigned short* a2 = Whhb;
        const float* a3 = b_hh;
        const float* a4 = gi;
        unsigned short* a5 = Hall;
        float* a6 = out + OUT_HID_OFF;
        unsigned int* a7 = bar;
        void* args[] = {&a0, &a1, &a2, &a3, &a4, &a5, &a6, &a7};
        hipLaunchCooperativeKernel((void*)gru_persistent, dim3(64), dim3(256),
                                   args, 0, stream);
    }

    gemm_logits<<<dim3(NBX, NBY), 256, 0, stream>>>(Hall, OutW, out_b, out, pstat);
    lsm_reduce<<<ROWS, 64, 0, stream>>>(pstat, stats);
    lsm_apply<<<2048, 256, 0, stream>>>(out, stats);
}